// Round 7
// baseline (150.759 us; speedup 1.0000x reference)
//
#include <hip/hip_runtime.h>

#define Dm  128
#define K1  64
#define LUT_ROWS 8    // LUT rows per prep block -> T/8 blocks (full-GPU parallel)
#define CAPE 512      // staged edges per block (16 segments ~ 256 +- 16 edges)
#define SEGB 16       // segments per block (one per 16-lane quarter)

typedef _Float16 h8 __attribute__((ext_vector_type(8)));

__device__ __forceinline__ float ssp(float x) {
    return __logf(1.0f + __expf(x)) - 0.69314718056f;
}

__device__ __forceinline__ unsigned int pack_h2f(float a, float b) {
    _Float16 v[2] = {(_Float16)a, (_Float16)b};
    unsigned int u;
    __builtin_memcpy(&u, v, 4);
    return u;
}

// Fused prep, 256 threads/block:
//   [0, LUTB):            NN filter LUT (midpoint), 8 rows/block
//   [LUTB, +CB):          convert atom_features f32 -> f16
//   [LUTB+CB, +RB):       row_ptr build (seg_i is sorted -> scatter boundaries)
// NOTE: no out-zeroing pass — cfconv writes every out row exactly once.
__global__ void prep_all(const float* __restrict__ centers,
                         const float* __restrict__ gamma,
                         const float* __restrict__ W1,
                         const float* __restrict__ b1,
                         const float* __restrict__ W2,
                         const float* __restrict__ b2,
                         const float* __restrict__ af,
                         const int*   __restrict__ seg_i,
                         _Float16* __restrict__ tab,
                         _Float16* __restrict__ afh,
                         int* __restrict__ rp,
                         int T, int LUTB, int CB, int RB,
                         int NATD, int E, int NAT) {
    __shared__ float rbf[LUT_ROWS][K1];    // 2 KB
    __shared__ float h1s[LUT_ROWS][Dm];    // 4 KB
    const int blk = blockIdx.x;
    const int t = threadIdx.x;             // 0..255

    if (blk < LUTB) {
        const int r0 = blk * LUT_ROWS;
        const float invT = 1.0f / (float)T;
        #pragma unroll
        for (int i = t; i < LUT_ROWS * K1; i += 256) {
            int r = i >> 6, k = i & 63;
            float d = ((float)(r0 + r) + 0.5f) * invT;   // midpoint sample
            float diff = d - centers[k];
            rbf[r][k] = __expf(-gamma[k] * diff * diff);
        }
        __syncthreads();
        const int ch = t & 127;
        const int rb = (t >> 7) * 4;       // rows [rb, rb+4)
        float acc[4];
        {
            float b = b1[ch];
            #pragma unroll
            for (int r = 0; r < 4; ++r) acc[r] = b;
        }
        #pragma unroll 4
        for (int k = 0; k < K1; ++k) {
            float w = W1[k * Dm + ch];
            #pragma unroll
            for (int r = 0; r < 4; ++r) acc[r] = fmaf(rbf[rb + r][k], w, acc[r]);
        }
        #pragma unroll
        for (int r = 0; r < 4; ++r) h1s[rb + r][ch] = ssp(acc[r]);
        __syncthreads();
        {
            float b = b2[ch];
            #pragma unroll
            for (int r = 0; r < 4; ++r) acc[r] = b;
        }
        #pragma unroll 4
        for (int k = 0; k < Dm; ++k) {
            float w = W2[k * Dm + ch];
            #pragma unroll
            for (int r = 0; r < 4; ++r) acc[r] = fmaf(h1s[rb + r][k], w, acc[r]);
        }
        #pragma unroll
        for (int r = 0; r < 4; ++r)
            tab[(size_t)(r0 + rb + r) * Dm + ch] = (_Float16)ssp(acc[r]);
    } else if (blk < LUTB + CB) {
        const int b = blk - LUTB;
        const float4* a4 = (const float4*)af;
        uint2* d4 = (uint2*)afh;
        const int n4 = NATD >> 2;
        for (int i = b * 256 + t; i < n4; i += CB * 256) {
            float4 v = a4[i];
            uint2 st;
            st.x = pack_h2f(v.x, v.y);
            st.y = pack_h2f(v.z, v.w);
            d4[i] = st;
        }
    } else if (RB > 0) {
        // row_ptr: rp[s] = lower_bound(seg_i, s); rp[NAT] = E.
        // Edge e owns the disjoint range (seg[e-1], seg[e]] -> rp[.] = e.
        const int b = blk - LUTB - CB;
        for (int e = b * 256 + t; e < E; e += RB * 256) {
            int se = seg_i[e];
            int sp = (e == 0) ? -1 : seg_i[e - 1];
            for (int ss = sp + 1; ss <= se; ++ss) rp[ss] = e;
            if (e == E - 1)
                for (int ss = se + 1; ss <= NAT; ++ss) rp[ss] = E;
        }
    }
}

// v11: atom-parallel CSR (v10 structure) + DUAL-CHAIN inner loop.
// v10 post-mortem: cfconv ~43 us, ~3x above the ~12-15 us cache-service
// floor. The per-quarter loop was a serial dependent chain (~16 edges,
// depth-1 prefetch -> ONE (tb,av) pair outstanding, ~600cy stall/edge).
// v11 splits each segment into even/odd chains with independent
// accumulators and independent depth-1 prefetch: 2x outstanding loads,
// half the chain depth, two independent FMA streams. Manual rotation with
// named registers (the mechanism R6 proved works; R4 proved the compiler
// won't do it for us). Final s = sA + sB (f32 reorder ~1e-6; absmax is
// pinned at the f16 input-quantization floor 2^-7).
template<bool AF16>
__global__ __launch_bounds__(256) void cfconv_v11(
    const float* __restrict__ af,
    const _Float16* __restrict__ afh,
    const float* __restrict__ distances,
    const int*   __restrict__ idx_j,
    const int*   __restrict__ seg_i,
    const int*   __restrict__ rp,      // may be null -> binary search
    const _Float16* __restrict__ tab,
    float* __restrict__ out, int T, int E, int NAT)
{
    __shared__ int2 metaE[CAPE];       // (idx_j, lut_row) per staged edge 4 KB
    __shared__ int  bnd[SEGB + 1];
    const int t  = threadIdx.x;
    const int s0 = blockIdx.x * SEGB;
    const float fT = (float)T;

    if (t < SEGB + 1) {
        int key = s0 + t; if (key > NAT) key = NAT;
        if (rp) {
            bnd[t] = rp[key];
        } else {                        // fallback: lower_bound(seg_i, key)
            int lo = 0, hi = E;
            while (lo < hi) {
                int mid = (lo + hi) >> 1;
                if (seg_i[mid] < key) lo = mid + 1; else hi = mid;
            }
            bnd[t] = lo;
        }
    }
    __syncthreads();
    const int ebase = bnd[0];
    const int ecnt  = bnd[SEGB] - ebase;

    for (int i = t; i < ecnt && i < CAPE; i += 256) {
        int e = ebase + i;
        int iv = (int)(distances[e] * fT);
        iv = iv < 0 ? 0 : (iv > T - 1 ? T - 1 : iv);
        metaE[i] = make_int2(idx_j[e], iv);
    }
    __syncthreads();

    const int q   = t >> 4;            // quarter 0..15 -> segment s0+q
    const int li  = t & 15;
    const int c8  = li * 8;            // 8 f16 channels owned by this lane
    const int end = bnd[q + 1];
    int eA = bnd[q];                   // even-position chain
    int eB = eA + 1;                   // odd-position chain

    float sA[8], sB[8];
    #pragma unroll
    for (int i = 0; i < 8; ++i) { sA[i] = 0.f; sB[i] = 0.f; }

    h8 tA, aA, tB, aB;

    auto fetch = [&](int e, h8& tb, h8& av) {
        int rel = e - ebase;
        int2 m;
        if (rel < CAPE) m = metaE[rel];
        else {                          // overflow edges (vanishingly rare)
            int iv = (int)(distances[e] * fT);
            iv = iv < 0 ? 0 : (iv > T - 1 ? T - 1 : iv);
            m = make_int2(idx_j[e], iv);
        }
        tb = *(const h8*)&tab[(size_t)m.y * Dm + c8];
        if (AF16) {
            av = *(const h8*)&afh[(size_t)m.x * Dm + c8];
        } else {
            float4 a0 = *(const float4*)&af[(size_t)m.x * Dm + c8];
            float4 a1 = *(const float4*)&af[(size_t)m.x * Dm + c8 + 4];
            av[0] = (_Float16)a0.x; av[1] = (_Float16)a0.y;
            av[2] = (_Float16)a0.z; av[3] = (_Float16)a0.w;
            av[4] = (_Float16)a1.x; av[5] = (_Float16)a1.y;
            av[6] = (_Float16)a1.z; av[7] = (_Float16)a1.w;
        }
    };

    // prologue: both chain heads in flight
    if (eA < end) fetch(eA, tA, aA);
    if (eB < end) fetch(eB, tB, aB);

    while (eA < end) {
        h8 cTA = tA, cAA = aA, cTB = tB, cAB = aB;
        const bool hB = (eB < end);
        const int nA = eA + 2, nB = eB + 2;
        // issue both prefetches before any consumption
        if (nA < end) fetch(nA, tA, aA);
        if (hB && nB < end) fetch(nB, tB, aB);
        #pragma unroll
        for (int i = 0; i < 8; ++i)   // v_fma_mix_f32: f16*f16 + f32
            sA[i] = fmaf((float)cTA[i], (float)cAA[i], sA[i]);
        if (hB) {
            #pragma unroll
            for (int i = 0; i < 8; ++i)
                sB[i] = fmaf((float)cTB[i], (float)cAB[i], sB[i]);
        }
        eA = nA; eB = nB;
    }

    const int sseg = s0 + q;
    if (sseg < NAT) {                  // exclusively-owned row: plain store
        float* op = &out[(size_t)sseg * Dm + c8];
        *(float4*)op       = make_float4(sA[0] + sB[0], sA[1] + sB[1],
                                         sA[2] + sB[2], sA[3] + sB[3]);
        *(float4*)(op + 4) = make_float4(sA[4] + sB[4], sA[5] + sB[5],
                                         sA[6] + sB[6], sA[7] + sB[7]);
    }
}

extern "C" void kernel_launch(void* const* d_in, const int* in_sizes, int n_in,
                              void* d_out, int out_size, void* d_ws, size_t ws_size,
                              hipStream_t stream) {
    const float* atom_features = (const float*)d_in[0];
    const float* distances     = (const float*)d_in[1];
    const int*   idx_j         = (const int*)d_in[2];
    const int*   seg_i         = (const int*)d_in[3];
    const float* centers       = (const float*)d_in[4];
    const float* gamma         = (const float*)d_in[5];
    const float* W1            = (const float*)d_in[6];
    const float* b1            = (const float*)d_in[7];
    const float* W2            = (const float*)d_in[8];
    const float* b2            = (const float*)d_in[9];

    const int E    = in_sizes[1];   // 800000
    const int NATD = out_size;      // 50000*128
    const int NAT  = NATD / Dm;     // 50000
    float* out = (float*)d_out;

    // ws layout: [tab: T*Dm*2][afh: NATD*2 (opt)][rp: (NAT+1)*4 (opt)]
    const size_t tab2048_b = (size_t)2048 * Dm * 2;
    const size_t afh_b     = (size_t)NATD * 2;
    const size_t rp_b      = (size_t)(NAT + 1) * 4;
    int T; bool af16, hasrp;
    if      (ws_size >= tab2048_b + afh_b + rp_b) { T = 2048; af16 = true;  hasrp = true;  }
    else if (ws_size >= tab2048_b + afh_b)        { T = 2048; af16 = true;  hasrp = false; }
    else if (ws_size >= tab2048_b + rp_b)         { T = 2048; af16 = false; hasrp = true;  }
    else if (ws_size >= tab2048_b)                { T = 2048; af16 = false; hasrp = false; }
    else                                          { T = 512;  af16 = false; hasrp = false; }

    char* p = (char*)d_ws;
    _Float16* tab = (_Float16*)p;
    _Float16* afh = af16 ? (_Float16*)(p + (size_t)T * Dm * 2) : nullptr;
    int* rp = hasrp
        ? (int*)(p + (size_t)T * Dm * 2 + (af16 ? afh_b : 0))
        : nullptr;

    const int LUTB = T / LUT_ROWS;      // 256 blocks at T=2048
    const int CB = af16 ? 256 : 0;
    const int RB = hasrp ? 64 : 0;
    prep_all<<<LUTB + CB + RB, 256, 0, stream>>>(
        centers, gamma, W1, b1, W2, b2, atom_features, seg_i,
        tab, afh, rp, T, LUTB, CB, RB, NATD, E, NAT);

    const int grid = (NAT + SEGB - 1) / SEGB;   // 3125
    if (af16)
        cfconv_v11<true><<<grid, 256, 0, stream>>>(
            atom_features, afh, distances, idx_j, seg_i, rp, tab, out, T, E, NAT);
    else
        cfconv_v11<false><<<grid, 256, 0, stream>>>(
            atom_features, afh, distances, idx_j, seg_i, rp, tab, out, T, E, NAT);
}

// Round 9
// 144.209 us; speedup vs baseline: 1.0454x; 1.0454x over previous
//
#include <hip/hip_runtime.h>

#define Dm  128
#define K1  64
#define LUT_ROWS 8    // LUT rows per prep block -> T/8 blocks (full-GPU parallel)
#define CAPE 512      // staged edges per block (16 segments ~ 256 +- 16 edges)
#define SEGB 16       // segments per block (one per 16-lane quarter)

typedef _Float16 h8 __attribute__((ext_vector_type(8)));

__device__ __forceinline__ float ssp(float x) {
    return __logf(1.0f + __expf(x)) - 0.69314718056f;
}

__device__ __forceinline__ unsigned int pack_h2f(float a, float b) {
    _Float16 v[2] = {(_Float16)a, (_Float16)b};
    unsigned int u;
    __builtin_memcpy(&u, v, 4);
    return u;
}

// Fused prep, 256 threads/block:
//   [0, LUTB):            NN filter LUT (midpoint), 8 rows/block
//   [LUTB, +CB):          convert atom_features f32 -> f16
//   [LUTB+CB, +RB):       row_ptr build (seg_i is sorted -> scatter boundaries)
// NOTE: no out-zeroing pass — cfconv writes every out row exactly once.
__global__ void prep_all(const float* __restrict__ centers,
                         const float* __restrict__ gamma,
                         const float* __restrict__ W1,
                         const float* __restrict__ b1,
                         const float* __restrict__ W2,
                         const float* __restrict__ b2,
                         const float* __restrict__ af,
                         const int*   __restrict__ seg_i,
                         _Float16* __restrict__ tab,
                         _Float16* __restrict__ afh,
                         int* __restrict__ rp,
                         int T, int LUTB, int CB, int RB,
                         int NATD, int E, int NAT) {
    __shared__ float rbf[LUT_ROWS][K1];    // 2 KB
    __shared__ float h1s[LUT_ROWS][Dm];    // 4 KB
    const int blk = blockIdx.x;
    const int t = threadIdx.x;             // 0..255

    if (blk < LUTB) {
        const int r0 = blk * LUT_ROWS;
        const float invT = 1.0f / (float)T;
        #pragma unroll
        for (int i = t; i < LUT_ROWS * K1; i += 256) {
            int r = i >> 6, k = i & 63;
            float d = ((float)(r0 + r) + 0.5f) * invT;   // midpoint sample
            float diff = d - centers[k];
            rbf[r][k] = __expf(-gamma[k] * diff * diff);
        }
        __syncthreads();
        const int ch = t & 127;
        const int rb = (t >> 7) * 4;       // rows [rb, rb+4)
        float acc[4];
        {
            float b = b1[ch];
            #pragma unroll
            for (int r = 0; r < 4; ++r) acc[r] = b;
        }
        #pragma unroll 4
        for (int k = 0; k < K1; ++k) {
            float w = W1[k * Dm + ch];
            #pragma unroll
            for (int r = 0; r < 4; ++r) acc[r] = fmaf(rbf[rb + r][k], w, acc[r]);
        }
        #pragma unroll
        for (int r = 0; r < 4; ++r) h1s[rb + r][ch] = ssp(acc[r]);
        __syncthreads();
        {
            float b = b2[ch];
            #pragma unroll
            for (int r = 0; r < 4; ++r) acc[r] = b;
        }
        #pragma unroll 4
        for (int k = 0; k < Dm; ++k) {
            float w = W2[k * Dm + ch];
            #pragma unroll
            for (int r = 0; r < 4; ++r) acc[r] = fmaf(h1s[rb + r][k], w, acc[r]);
        }
        #pragma unroll
        for (int r = 0; r < 4; ++r)
            tab[(size_t)(r0 + rb + r) * Dm + ch] = (_Float16)ssp(acc[r]);
    } else if (blk < LUTB + CB) {
        const int b = blk - LUTB;
        const float4* a4 = (const float4*)af;
        uint2* d4 = (uint2*)afh;
        const int n4 = NATD >> 2;
        for (int i = b * 256 + t; i < n4; i += CB * 256) {
            float4 v = a4[i];
            uint2 st;
            st.x = pack_h2f(v.x, v.y);
            st.y = pack_h2f(v.z, v.w);
            d4[i] = st;
        }
    } else if (RB > 0) {
        // row_ptr: rp[s] = lower_bound(seg_i, s); rp[NAT] = E.
        // Edge e owns the disjoint range (seg[e-1], seg[e]] -> rp[.] = e.
        const int b = blk - LUTB - CB;
        for (int e = b * 256 + t; e < E; e += RB * 256) {
            int se = seg_i[e];
            int sp = (e == 0) ? -1 : seg_i[e - 1];
            for (int ss = sp + 1; ss <= se; ++ss) rp[ss] = e;
            if (e == E - 1)
                for (int ss = se + 1; ss <= NAT; ++ss) rp[ss] = E;
        }
    }
}

// v12b: atom-parallel CSR (v10 structure) with issue-count reduction.
// R7: dual-chain regressed -> latency TLP-covered; kernel is ISSUE-bound.
// R8: v12 FAILED on one line — store used coff>>2 (li*4) instead of
//     coff>>1 (li*8): byte-offset (f16) vs element-offset (f32) unit bug.
//     Fixed here; all else identical to v12.
// Issue reduction vs v10 (~27 -> ~17 instrs/edge):
//   - metaE holds PRE-SCALED byte offsets (idx<<8, lut<<8), computed once
//     in the coalesced staging loop instead of per-lane per-iteration.
//   - uniform-base + 32-bit voffset loads: (char*)tab + (m.y + coff),
//     coff = li*16 bytes -> saddr global_load + 1 v_add each.
//   - unroll-2 with ALTERNATING register pairs (t0/a0 <-> t1/a1): zero
//     rotation movs, depth-1..2 prefetch, sequential accumulation order
//     (absmax bit-identical to v10).
//   - rel-indexed loop (no per-iteration e-ebase subtract).
template<bool AF16>
__global__ __launch_bounds__(256) void cfconv_v12(
    const float* __restrict__ af,
    const _Float16* __restrict__ afh,
    const float* __restrict__ distances,
    const int*   __restrict__ idx_j,
    const int*   __restrict__ seg_i,
    const int*   __restrict__ rp,      // may be null -> binary search
    const _Float16* __restrict__ tab,
    float* __restrict__ out, int T, int E, int NAT)
{
    __shared__ int2 metaE[CAPE];       // (idx_j<<8, lut_row<<8) per edge 4 KB
    __shared__ int  bnd[SEGB + 1];
    const int t  = threadIdx.x;
    const int s0 = blockIdx.x * SEGB;
    const float fT = (float)T;

    if (t < SEGB + 1) {
        int key = s0 + t; if (key > NAT) key = NAT;
        if (rp) {
            bnd[t] = rp[key];
        } else {                        // fallback: lower_bound(seg_i, key)
            int lo = 0, hi = E;
            while (lo < hi) {
                int mid = (lo + hi) >> 1;
                if (seg_i[mid] < key) lo = mid + 1; else hi = mid;
            }
            bnd[t] = lo;
        }
    }
    __syncthreads();
    const int ebase = bnd[0];
    const int ecnt  = bnd[SEGB] - ebase;

    for (int i = t; i < ecnt && i < CAPE; i += 256) {
        int e = ebase + i;
        int iv = (int)(distances[e] * fT);
        iv = iv < 0 ? 0 : (iv > T - 1 ? T - 1 : iv);
        metaE[i] = make_int2(idx_j[e] << 8, iv << 8);  // byte offsets (256B rows)
    }
    __syncthreads();

    const int q    = t >> 4;           // quarter 0..15 -> segment s0+q
    const int li   = t & 15;
    const int coff = li * 16;          // BYTE offset of this lane's 8 f16
    const int rs   = bnd[q]     - ebase;
    const int re   = bnd[q + 1] - ebase;

    float s[8];
    #pragma unroll
    for (int i = 0; i < 8; ++i) s[i] = 0.f;

    h8 t0, a0, t1, a1;

    auto FETCH = [&](int rel, h8& tb, h8& av) {
        int2 m;
        if (rel < CAPE) {
            m = metaE[rel];
        } else {                        // overflow edges (vanishingly rare)
            int e = ebase + rel;
            int iv = (int)(distances[e] * fT);
            iv = iv < 0 ? 0 : (iv > T - 1 ? T - 1 : iv);
            m = make_int2(idx_j[e] << 8, iv << 8);
        }
        tb = *(const h8*)((const char*)tab + (unsigned)(m.y + coff));
        if (AF16) {
            av = *(const h8*)((const char*)afh + (unsigned)(m.x + coff));
        } else {
            const char* ap = (const char*)af
                           + (((size_t)(unsigned)m.x) << 1) + ((unsigned)coff << 1);
            float4 f0 = *(const float4*)ap;
            float4 f1 = *(const float4*)(ap + 16);
            av[0] = (_Float16)f0.x; av[1] = (_Float16)f0.y;
            av[2] = (_Float16)f0.z; av[3] = (_Float16)f0.w;
            av[4] = (_Float16)f1.x; av[5] = (_Float16)f1.y;
            av[6] = (_Float16)f1.z; av[7] = (_Float16)f1.w;
        }
    };
    auto FMA = [&](const h8& tb, const h8& av) {
        #pragma unroll
        for (int i = 0; i < 8; ++i)    // v_fma_mix_f32: f16*f16 + f32
            s[i] = fmaf((float)tb[i], (float)av[i], s[i]);
    };

    const int n = re - rs;
    if (n > 0) {
        FETCH(rs, t0, a0);
        int i = 0;
        for (; i + 1 < n; i += 2) {    // unroll-2, alternating reg pairs
            FETCH(rs + i + 1, t1, a1);
            FMA(t0, a0);
            if (i + 2 < n) FETCH(rs + i + 2, t0, a0);
            FMA(t1, a1);
        }
        if (i < n) FMA(t0, a0);        // odd tail: payload already resident
    }

    const int sseg = s0 + q;
    if (sseg < NAT) {                  // exclusively-owned row: plain store
        // coff is BYTES over f16 (li*16) -> f32 element index = coff>>1 = li*8.
        // (R8 failure: coff>>2 wrote overlapping quarter-rows.)
        float* op = &out[(size_t)sseg * Dm + (coff >> 1)];
        *(float4*)op       = make_float4(s[0], s[1], s[2], s[3]);
        *(float4*)(op + 4) = make_float4(s[4], s[5], s[6], s[7]);
    }
}

extern "C" void kernel_launch(void* const* d_in, const int* in_sizes, int n_in,
                              void* d_out, int out_size, void* d_ws, size_t ws_size,
                              hipStream_t stream) {
    const float* atom_features = (const float*)d_in[0];
    const float* distances     = (const float*)d_in[1];
    const int*   idx_j         = (const int*)d_in[2];
    const int*   seg_i         = (const int*)d_in[3];
    const float* centers       = (const float*)d_in[4];
    const float* gamma         = (const float*)d_in[5];
    const float* W1            = (const float*)d_in[6];
    const float* b1            = (const float*)d_in[7];
    const float* W2            = (const float*)d_in[8];
    const float* b2            = (const float*)d_in[9];

    const int E    = in_sizes[1];   // 800000
    const int NATD = out_size;      // 50000*128
    const int NAT  = NATD / Dm;     // 50000
    float* out = (float*)d_out;

    // ws layout: [tab: T*Dm*2][afh: NATD*2 (opt)][rp: (NAT+1)*4 (opt)]
    const size_t tab2048_b = (size_t)2048 * Dm * 2;
    const size_t afh_b     = (size_t)NATD * 2;
    const size_t rp_b      = (size_t)(NAT + 1) * 4;
    int T; bool af16, hasrp;
    if      (ws_size >= tab2048_b + afh_b + rp_b) { T = 2048; af16 = true;  hasrp = true;  }
    else if (ws_size >= tab2048_b + afh_b)        { T = 2048; af16 = true;  hasrp = false; }
    else if (ws_size >= tab2048_b + rp_b)         { T = 2048; af16 = false; hasrp = true;  }
    else if (ws_size >= tab2048_b)                { T = 2048; af16 = false; hasrp = false; }
    else                                          { T = 512;  af16 = false; hasrp = false; }

    char* p = (char*)d_ws;
    _Float16* tab = (_Float16*)p;
    _Float16* afh = af16 ? (_Float16*)(p + (size_t)T * Dm * 2) : nullptr;
    int* rp = hasrp
        ? (int*)(p + (size_t)T * Dm * 2 + (af16 ? afh_b : 0))
        : nullptr;

    const int LUTB = T / LUT_ROWS;      // 256 blocks at T=2048
    const int CB = af16 ? 256 : 0;
    const int RB = hasrp ? 64 : 0;
    prep_all<<<LUTB + CB + RB, 256, 0, stream>>>(
        centers, gamma, W1, b1, W2, b2, atom_features, seg_i,
        tab, afh, rp, T, LUTB, CB, RB, NATD, E, NAT);

    const int grid = (NAT + SEGB - 1) / SEGB;   // 3125
    if (af16)
        cfconv_v12<true><<<grid, 256, 0, stream>>>(
            atom_features, afh, distances, idx_j, seg_i, rp, tab, out, T, E, NAT);
    else
        cfconv_v12<false><<<grid, 256, 0, stream>>>(
            atom_features, afh, distances, idx_j, seg_i, rp, tab, out, T, E, NAT);
}